// Round 1
// baseline (114.507 us; speedup 1.0000x reference)
//
#include <hip/hip_runtime.h>
#include <cstdint>
#include <cstddef>

constexpr int BB = 16, CC = 3, HH = 512, WW = 512;
constexpr int HW = HH * WW;
constexpr float RATIO = 0.12f;

// ws layout: [0..BB) uint min-bits, [BB..2*BB) uint max-bits, img_v at byte 256.
// Values are non-negative floats, so uint bit ordering == float ordering.

__global__ void init_mm(unsigned int* mm) {
    int i = threadIdx.x;
    if (i < BB)            mm[i] = 0x7F800000u;  // +inf  (min identity)
    else if (i < 2 * BB)   mm[i] = 0u;           // 0     (max identity, vals >= 0)
}

template <bool STORE_V>
__global__ __launch_bounds__(256) void k1_chanmax_minmax(
        const float* __restrict__ img, unsigned int* __restrict__ mm,
        float* __restrict__ imgv) {
    int t    = blockIdx.x * 256 + threadIdx.x;
    int off4 = t << 2;                 // 4 pixels per thread
    int b    = off4 / HW;              // uniform per block (256 blocks/image)
    int off  = off4 - b * HW;
    const float* base = img + (size_t)b * CC * HW + off;
    float4 c0 = *(const float4*)(base);
    float4 c1 = *(const float4*)(base + HW);
    float4 c2 = *(const float4*)(base + 2 * HW);
    float v0 = fmaxf(fmaxf(c0.x, c1.x), c2.x);
    float v1 = fmaxf(fmaxf(c0.y, c1.y), c2.y);
    float v2 = fmaxf(fmaxf(c0.z, c1.z), c2.z);
    float v3 = fmaxf(fmaxf(c0.w, c1.w), c2.w);
    if (STORE_V)
        *(float4*)(imgv + (size_t)b * HW + off) = make_float4(v0, v1, v2, v3);

    float mn = fminf(fminf(v0, v1), fminf(v2, v3));
    float mx = fmaxf(fmaxf(v0, v1), fmaxf(v2, v3));
    #pragma unroll
    for (int s = 32; s > 0; s >>= 1) {
        mn = fminf(mn, __shfl_xor(mn, s, 64));
        mx = fmaxf(mx, __shfl_xor(mx, s, 64));
    }
    __shared__ float smn[4], smx[4];
    int wave = threadIdx.x >> 6;
    if ((threadIdx.x & 63) == 0) { smn[wave] = mn; smx[wave] = mx; }
    __syncthreads();
    if (threadIdx.x == 0) {
        float m0 = fminf(fminf(smn[0], smn[1]), fminf(smn[2], smn[3]));
        float m1 = fmaxf(fmaxf(smx[0], smx[1]), fmaxf(smx[2], smx[3]));
        atomicMin(&mm[b],      __float_as_uint(m0));
        atomicMax(&mm[BB + b], __float_as_uint(m1));
    }
}

template <bool USE_IMGV>
__device__ inline void load_row(const float* __restrict__ img,
                                const float* __restrict__ imgv,
                                int b, int hh, int c, float v[6]) {
    int cm1 = max(c - 1, 0);
    int cp4 = min(c + 4, WW - 1);
    if (USE_IMGV) {
        const float* base = imgv + (size_t)b * HW + hh * WW;
        v[0] = base[cm1];
        float4 q = *(const float4*)(base + c);
        v[1] = q.x; v[2] = q.y; v[3] = q.z; v[4] = q.w;
        v[5] = base[cp4];
    } else {
        const float* base = img + (size_t)b * CC * HW + hh * WW;
        float4 a0 = *(const float4*)(base + c);
        float4 a1 = *(const float4*)(base + HW + c);
        float4 a2 = *(const float4*)(base + 2 * HW + c);
        v[1] = fmaxf(fmaxf(a0.x, a1.x), a2.x);
        v[2] = fmaxf(fmaxf(a0.y, a1.y), a2.y);
        v[3] = fmaxf(fmaxf(a0.z, a1.z), a2.z);
        v[4] = fmaxf(fmaxf(a0.w, a1.w), a2.w);
        v[0] = fmaxf(fmaxf(base[cm1], base[HW + cm1]), base[2 * HW + cm1]);
        v[5] = fmaxf(fmaxf(base[cp4], base[HW + cp4]), base[2 * HW + cp4]);
    }
}

template <bool USE_IMGV>
__global__ __launch_bounds__(256) void k2_edges(
        const float* __restrict__ img, const float* __restrict__ imgv,
        const unsigned int* __restrict__ mm, float* __restrict__ out) {
    int t = blockIdx.x * 256 + threadIdx.x;
    int r = t >> 7;             // row index over B*H (128 vec4-cols per row)
    int c = (t & 127) << 2;     // column base (multiple of 4 -> aligned float4)
    int b = r / HH;
    int h = r - b * HH;
    float thr = (__uint_as_float(mm[BB + b]) - __uint_as_float(mm[b])) * RATIO;
    int hm = max(h - 1, 0), hp = min(h + 1, HH - 1);

    float vt[6], vm[6], vp[6];
    load_row<USE_IMGV>(img, imgv, b, hm, c, vt);
    load_row<USE_IMGV>(img, imgv, b, h,  c, vm);
    load_row<USE_IMGV>(img, imgv, b, hp, c, vp);

    // v[k] holds column (c + k - 1), rows clamped.  For pixel i and stencil
    // (px,py): row = {0:vt,1:vm,2:vp}[px], index = i + py.
    float o[8][2][4];
    #pragma unroll
    for (int i = 0; i < 4; ++i) {
        float d[8];
        d[0] = vm[i]     - vp[i + 2];   // (1,0)-(2,2)
        d[1] = vt[i + 2] - vm[i];       // (0,2)-(1,0)
        d[2] = vp[i + 1] - vt[i + 2];   // (2,1)-(0,2)
        d[3] = vt[i]     - vp[i + 1];   // (0,0)-(2,1)
        d[4] = vm[i + 2] - vm[i + 1];   // (1,2)-(1,1)
        d[5] = vt[i + 1] - vm[i + 1];   // (0,1)-(1,1)
        d[6] = vt[i + 2] - vm[i + 1];   // (0,2)-(1,1)
        d[7] = vt[i]     - vm[i + 1];   // (0,0)-(1,1)
        #pragma unroll
        for (int f = 0; f < 8; ++f) {
            float pos = fmaxf(d[f], 0.0f);
            float neg = fmaxf(-d[f], 0.0f);
            o[f][0][i] = (pos >= thr) ? 1.0f : 0.0f;
            o[f][1][i] = (neg >= thr) ? 1.0f : 0.0f;
        }
    }
    size_t pixoff = (size_t)h * WW + c;
    #pragma unroll
    for (int f = 0; f < 8; ++f) {
        #pragma unroll
        for (int s = 0; s < 2; ++s) {
            float4 q = make_float4(o[f][s][0], o[f][s][1], o[f][s][2], o[f][s][3]);
            *(float4*)(out + ((size_t)((f * BB + b) * 2 + s)) * HW + pixoff) = q;
        }
    }
}

extern "C" void kernel_launch(void* const* d_in, const int* in_sizes, int n_in,
                              void* d_out, int out_size, void* d_ws, size_t ws_size,
                              hipStream_t stream) {
    const float* img = (const float*)d_in[0];
    float* out = (float*)d_out;
    unsigned int* mm = (unsigned int*)d_ws;
    float* imgv = (float*)((char*)d_ws + 256);
    size_t need = 256 + (size_t)BB * HW * sizeof(float);
    bool use_imgv = (ws_size >= need);

    init_mm<<<1, 64, 0, stream>>>(mm);
    int blocks = BB * HW / (256 * 4);   // 4096
    if (use_imgv) {
        k1_chanmax_minmax<true><<<blocks, 256, 0, stream>>>(img, mm, imgv);
        k2_edges<true><<<blocks, 256, 0, stream>>>(img, imgv, mm, out);
    } else {
        k1_chanmax_minmax<false><<<blocks, 256, 0, stream>>>(img, mm, nullptr);
        k2_edges<false><<<blocks, 256, 0, stream>>>(img, nullptr, mm, out);
    }
}